// Round 1
// baseline (7818.396 us; speedup 1.0000x reference)
//
#include <hip/hip_runtime.h>
#include <stdint.h>

typedef unsigned short u16;
typedef __attribute__((ext_vector_type(8))) short bh8;        // 8 bf16 raw (4 VGPRs)
typedef __attribute__((ext_vector_type(8))) unsigned short u16x8;
typedef __attribute__((ext_vector_type(4))) float f32x4;

#define B_ 32
#define T_ 1000
#define D_ 512
#define NG 2048   // 4*D

__device__ __forceinline__ float bf2f(u16 u) {
  union { unsigned int i; float f; } v; v.i = ((unsigned int)u) << 16; return v.f;
}
__device__ __forceinline__ u16 f2bf(float f) {
  union { float f; unsigned int i; } v; v.f = f;
  return (u16)((v.i + 0x7fffu + ((v.i >> 16) & 1u)) >> 16);   // RNE
}

// ---------------- weight transpose + f32->bf16 : dst[C][R] = src[R][C] ----------------
__global__ __launch_bounds__(256) void wtrans_k(const float* __restrict__ src,
                                                u16* __restrict__ dst, int R, int C) {
  __shared__ float tile[32][33];
  const int r0 = blockIdx.x * 32, c0 = blockIdx.y * 32;
  const int tid = threadIdx.x;
#pragma unroll
  for (int q = 0; q < 4; q++) {
    int idx = q * 256 + tid, rr = idx >> 5, cc = idx & 31;
    tile[rr][cc] = src[(size_t)(r0 + rr) * C + c0 + cc];
  }
  __syncthreads();
#pragma unroll
  for (int q = 0; q < 4; q++) {
    int idx = q * 256 + tid, cc = idx >> 5, rr = idx & 31;
    dst[(size_t)(c0 + cc) * R + r0 + rr] = f2bf(tile[rr][cc]);
  }
}

__global__ void bsum_k(const float* __restrict__ a, const float* __restrict__ b,
                       float* __restrict__ o) {
  int i = blockIdx.x * blockDim.x + threadIdx.x;
  if (i < NG) o[i] = a[i] + b[i];
}

// ---------------- x[:, 0:512] = emb[zi[b][t-1]] (0 for t==0), rows ordered (t,b) ----------------
__global__ __launch_bounds__(256) void embed_k(const int* __restrict__ zi,
                                               const float* __restrict__ emb,
                                               u16* __restrict__ x) {
  const int tid = threadIdx.x;
  const int r = blockIdx.x * 4 + (tid >> 6);        // (t*32+b), grid 8000
  const int d0 = (tid & 63) * 8;
  const int t = r >> 5, b = r & 31;
  u16x8 o;
  if (t == 0) {
#pragma unroll
    for (int i = 0; i < 8; i++) o[i] = 0;
  } else {
    const int zv = zi[b * T_ + t - 1];
    const float* s = emb + (size_t)zv * D_ + d0;
#pragma unroll
    for (int i = 0; i < 8; i++) o[i] = f2bf(s[i]);
  }
  *(u16x8*)(x + (size_t)r * 1024 + d0) = o;
}

// ---------------- x[:, 512:1024] = c[b][d][t] transposed (LDS tile) ----------------
__global__ __launch_bounds__(256) void ctrans_k(const float* __restrict__ c,
                                                u16* __restrict__ x) {
  __shared__ float tile[32][65];
  const int b = blockIdx.z, d0 = blockIdx.y * 32, t0 = blockIdx.x * 64;
  const int tid = threadIdx.x;
  const int dd = tid >> 3, tt0 = (tid & 7) * 8;
  const float* src = c + ((size_t)b * D_ + d0 + dd) * T_ + t0 + tt0;
#pragma unroll
  for (int i = 0; i < 8; i++) {
    int tt = tt0 + i;
    tile[dd][tt] = (t0 + tt < T_) ? src[i] : 0.f;
  }
  __syncthreads();
  const int tt = tid & 63, dq = tid >> 6;
  if (t0 + tt < T_) {
    u16x8 o;
#pragma unroll
    for (int i = 0; i < 8; i++) o[i] = f2bf(tile[dq * 8 + i][tt]);
    *(u16x8*)(x + ((size_t)(t0 + tt) * 32 + b) * 1024 + 512 + d0 + dq * 8) = o;
  }
}

// ---------------- bf16 MFMA GEMM: C[M,N] = act(A[M,K] @ Bt[N,K]^T + bias) ----------------
// 128x128 tile, BK=32, 4 waves, reg-staged LDS (padded stride 40 to kill bank conflicts)
template <bool RELU, bool SCATTER>
__global__ __launch_bounds__(256, 2) void gemm_k(const u16* __restrict__ A,
                                                 const u16* __restrict__ Bt,
                                                 const float* __restrict__ bias,
                                                 void* __restrict__ Cout,
                                                 int M, int N, int K) {
  __shared__ u16 Al[128 * 40];
  __shared__ u16 Bl[128 * 40];
  const int tid = threadIdx.x;
  const int w = tid >> 6, l = tid & 63;
  const int row0 = blockIdx.x * 128, col0 = blockIdx.y * 128;
  const int wr = (w >> 1) * 64, wc = (w & 1) * 64;
  f32x4 acc[4][4];
  const f32x4 zero = {0.f, 0.f, 0.f, 0.f};
#pragma unroll
  for (int i = 0; i < 4; i++)
#pragma unroll
    for (int j = 0; j < 4; j++) acc[i][j] = zero;

  const int sm = tid >> 2;          // staging row 0..63 (+64 for second half)
  const int sk = (tid & 3) * 8;     // k-chunk
  const u16* Ap = A + (size_t)(row0 + sm) * K + sk;
  const u16* Bp = Bt + (size_t)(col0 + sm) * K + sk;
  const size_t half = (size_t)64 * K;
  const int ldo = sm * 40 + sk;
  const int lr = l & 15, lk = (l >> 4) * 8;
  const int KT = K >> 5;

  bh8 a0 = *(const bh8*)Ap, a1 = *(const bh8*)(Ap + half);
  bh8 b0 = *(const bh8*)Bp, b1 = *(const bh8*)(Bp + half);

  for (int kt = 0; kt < KT; kt++) {
    const int kn = (kt + 1 < KT) ? (kt + 1) * 32 : 0;   // clamped (never OOB)
    bh8 na0 = *(const bh8*)(Ap + kn), na1 = *(const bh8*)(Ap + half + kn);
    bh8 nb0 = *(const bh8*)(Bp + kn), nb1 = *(const bh8*)(Bp + half + kn);
    *(bh8*)(Al + ldo) = a0;
    *(bh8*)(Al + ldo + 64 * 40) = a1;
    *(bh8*)(Bl + ldo) = b0;
    *(bh8*)(Bl + ldo + 64 * 40) = b1;
    __syncthreads();
    bh8 af[4], bfr[4];
#pragma unroll
    for (int i = 0; i < 4; i++) af[i] = *(const bh8*)(Al + (wr + i * 16 + lr) * 40 + lk);
#pragma unroll
    for (int j = 0; j < 4; j++) bfr[j] = *(const bh8*)(Bl + (wc + j * 16 + lr) * 40 + lk);
#pragma unroll
    for (int i = 0; i < 4; i++)
#pragma unroll
      for (int j = 0; j < 4; j++)
        acc[i][j] = __builtin_amdgcn_mfma_f32_16x16x32_bf16(af[i], bfr[j], acc[i][j], 0, 0, 0);
    __syncthreads();
    a0 = na0; a1 = na1; b0 = nb0; b1 = nb1;
  }

  const int lrow = (l >> 4) * 4;
#pragma unroll
  for (int j = 0; j < 4; j++) {
    const int n = col0 + wc + j * 16 + lr;
    const float bv = bias[n];
#pragma unroll
    for (int i = 0; i < 4; i++) {
      const int r = row0 + wr + i * 16 + lrow;
      if (SCATTER) {  // out[b][n][t], r = b*T_+t ; 4 acc elems = 4 consecutive t
        const int bb = r / T_;
        const int t = r - bb * T_;
        f32x4 o;
#pragma unroll
        for (int e = 0; e < 4; e++) o[e] = acc[i][j][e] + bv;
        *(f32x4*)((float*)Cout + ((size_t)bb * N + n) * T_ + t) = o;
      } else {
#pragma unroll
        for (int e = 0; e < 4; e++) {
          float v = acc[i][j][e] + bv;
          if (RELU) v = v > 0.f ? v : 0.f;
          ((u16*)Cout)[(size_t)(r + e) * N + n] = f2bf(v);
        }
      }
    }
  }
}

// ---------------- persistent LSTM scan: 32 wgs x 512 thr, wg j owns h-dims [16j,16j+16) ----------------
__global__ __launch_bounds__(512, 1) void scan_k(const u16* __restrict__ xg,   // [T*B][2048] (t,b)
                                                 const u16* __restrict__ Whht, // [2048][512]
                                                 u16* __restrict__ hs,         // [B*T][512] (b,t)
                                                 u16* hbuf,                    // [2][32][512]
                                                 unsigned int* cnt) {          // [T_]
  __shared__ u16 h_lds[32 * 520];          // h_{t-1}, padded stride 520
  __shared__ float gl[4][32][16];          // gate partials [g][b][d]
  const int tid = threadIdx.x;
  const int wg = blockIdx.x;
  const int dbase = wg * 16;
  const int w = tid >> 6, l = tid & 63;
  const int mi = w >> 2, ni = w & 3;       // wave -> (batch-half, gate)
  const int lr = l & 15, lk8 = (l >> 4) * 8;

  // loop-invariant B fragments: Whh^T rows = gate cols (ni*512 + dbase + lr)
  bh8 bfr[16];
  {
    const u16* wp = Whht + (size_t)(ni * 512 + dbase + lr) * 512 + lk8;
#pragma unroll
    for (int kk = 0; kk < 16; kk++) bfr[kk] = *(const bh8*)(wp + kk * 32);
  }
  for (int i = tid; i < 32 * 520; i += 512) h_lds[i] = 0;   // h_{-1} = 0

  const int pb = tid >> 4, pd = tid & 15;  // pointwise thread -> (batch, dim)
  float ccv = 0.f;                         // cell state, fp32 in-register
  float xgv[4];
  {
    const u16* xp = xg + (size_t)pb * NG + dbase + pd;      // t = 0
#pragma unroll
    for (int g = 0; g < 4; g++) xgv[g] = bf2f(xp[g * 512]);
  }
  __syncthreads();

  for (int t = 0; t < T_; t++) {
    f32x4 acc = {0.f, 0.f, 0.f, 0.f};
#pragma unroll
    for (int kk = 0; kk < 16; kk++) {
      bh8 af = *(const bh8*)(h_lds + (mi * 16 + lr) * 520 + kk * 32 + lk8);
      acc = __builtin_amdgcn_mfma_f32_16x16x32_bf16(af, bfr[kk], acc, 0, 0, 0);
    }
#pragma unroll
    for (int e = 0; e < 4; e++) gl[ni][mi * 16 + (l >> 4) * 4 + e][lr] = acc[e];
    __syncthreads();                                        // B1

    const float gi = gl[0][pb][pd] + xgv[0];
    const float gf = gl[1][pb][pd] + xgv[1];
    const float gg = gl[2][pb][pd] + xgv[2];
    const float go = gl[3][pb][pd] + xgv[3];
    const float si = 1.f / (1.f + __expf(-gi));
    const float sf = 1.f / (1.f + __expf(-gf));
    const float e2g = __expf(2.f * gg);
    const float sg = 1.f - 2.f / (e2g + 1.f);
    const float so = 1.f / (1.f + __expf(-go));
    ccv = sf * ccv + si * sg;
    const float e2c = __expf(2.f * ccv);
    const float hv = so * (1.f - 2.f / (e2c + 1.f));
    const u16 hb = f2bf(hv);
    hs[((size_t)pb * T_ + t) * 512 + dbase + pd] = hb;
    __hip_atomic_store(hbuf + ((size_t)(t & 1) * 32 + pb) * 512 + dbase + pd, hb,
                       __ATOMIC_RELAXED, __HIP_MEMORY_SCOPE_AGENT);
    __syncthreads();                                        // B2 (drains stores)

    if (t + 1 < T_) {
      {  // prefetch next xg while waiting
        const u16* xp = xg + ((size_t)(t + 1) * 32 + pb) * NG + dbase + pd;
#pragma unroll
        for (int g = 0; g < 4; g++) xgv[g] = bf2f(xp[g * 512]);
      }
      if (tid == 0) {
        __hip_atomic_fetch_add(cnt + t, 1u, __ATOMIC_RELEASE, __HIP_MEMORY_SCOPE_AGENT);
        while (__hip_atomic_load(cnt + t, __ATOMIC_ACQUIRE, __HIP_MEMORY_SCOPE_AGENT) < 32u)
          __builtin_amdgcn_s_sleep(2);
      }
      __syncthreads();                                      // B3
      {  // gather full h_t into LDS (agent-scope -> coherent reads)
        const int b2 = tid >> 4, dp0 = (tid & 15) * 16;
        const unsigned int* src =
            (const unsigned int*)hbuf + ((size_t)(t & 1) * 32 + b2) * 256 + dp0;
        unsigned int* dw = (unsigned int*)(h_lds + (size_t)b2 * 520);
#pragma unroll
        for (int i = 0; i < 16; i++) {
          unsigned int v = __hip_atomic_load(src + i, __ATOMIC_RELAXED, __HIP_MEMORY_SCOPE_AGENT);
          dw[dp0 + i] = v;
        }
      }
      __syncthreads();                                      // B4
    }
  }
}

extern "C" void kernel_launch(void* const* d_in, const int* in_sizes, int n_in,
                              void* d_out, int out_size, void* d_ws, size_t ws_size,
                              hipStream_t stream) {
  const int*   zi    = (const int*)d_in[0];
  const float* c     = (const float*)d_in[1];
  const float* emb   = (const float*)d_in[2];
  const float* W1    = (const float*)d_in[3];
  const float* b1    = (const float*)d_in[4];
  const float* W2    = (const float*)d_in[5];
  const float* b2    = (const float*)d_in[6];
  const float* W_ih  = (const float*)d_in[7];
  const float* b_ih  = (const float*)d_in[8];
  const float* W_hh  = (const float*)d_in[9];
  const float* b_hh  = (const float*)d_in[10];
  const float* W_out = (const float*)d_in[11];
  const float* b_out = (const float*)d_in[12];
  float* out = (float*)d_out;
  char* ws = (char*)d_ws;

  // workspace map (lifetime-aliased):
  //   [0, 65.5M)    x (bf16, (t,b) rows)   ; later: hs in [0,32.8M), pre in [32.8M,65.5M)
  //   [65.5M,196.6M) xg (bf16)             ; h1 aliases its first 32.8M (dead before GEMM3)
  //   [196.6M, ...)  weights/bsum/hbuf/cnt
  const size_t x_off   = 0;
  const size_t xg_off  = 65536000;
  const size_t pre_off = 32768000;
  const size_t w_off   = xg_off + 131072000;
  u16* xb    = (u16*)(ws + x_off);
  u16* hsb   = (u16*)(ws + x_off);
  u16* preb  = (u16*)(ws + pre_off);
  u16* xgb   = (u16*)(ws + xg_off);
  u16* h1b   = (u16*)(ws + xg_off);
  u16* W1t   = (u16*)(ws + w_off);           // [512][1024]
  u16* W2t   = W1t + 512 * 1024;             // [512][512]
  u16* Wiht  = W2t + 512 * 512;              // [2048][512]
  u16* Whht  = Wiht + 2048 * 512;            // [2048][512]
  u16* Woutt = Whht + 2048 * 512;            // [512][512]
  float* bsum = (float*)(Woutt + 512 * 512);
  u16* hbuf  = (u16*)(bsum + NG);
  unsigned int* cnt = (unsigned int*)(hbuf + 2 * 32 * 512);

  hipMemsetAsync(cnt, 0, T_ * sizeof(unsigned int), stream);

  wtrans_k<<<dim3(32, 16), 256, 0, stream>>>(W1, W1t, 1024, 512);
  wtrans_k<<<dim3(16, 16), 256, 0, stream>>>(W2, W2t, 512, 512);
  wtrans_k<<<dim3(16, 64), 256, 0, stream>>>(W_ih, Wiht, 512, 2048);
  wtrans_k<<<dim3(16, 64), 256, 0, stream>>>(W_hh, Whht, 512, 2048);
  wtrans_k<<<dim3(16, 16), 256, 0, stream>>>(W_out, Woutt, 512, 512);
  bsum_k<<<8, 256, 0, stream>>>(b_ih, b_hh, bsum);
  embed_k<<<8000, 256, 0, stream>>>(zi, emb, xb);
  ctrans_k<<<dim3(16, 16, 32), 256, 0, stream>>>(c, xb);

  gemm_k<true,  false><<<dim3(250, 4),  256, 0, stream>>>(xb,   W1t,   b1,   h1b, 32000, 512,  1024);
  gemm_k<false, false><<<dim3(250, 4),  256, 0, stream>>>(h1b,  W2t,   b2,   preb, 32000, 512,  512);
  gemm_k<false, false><<<dim3(250, 16), 256, 0, stream>>>(preb, Wiht,  bsum, xgb, 32000, 2048, 512);
  scan_k<<<32, 512, 0, stream>>>(xgb, Whht, hsb, hbuf, cnt);
  gemm_k<false, true ><<<dim3(250, 4),  256, 0, stream>>>(hsb,  Woutt, b_out, out, 32000, 512, 512);
}

// Round 2
// 5323.182 us; speedup vs baseline: 1.4687x; 1.4687x over previous
//
#include <hip/hip_runtime.h>
#include <stdint.h>

typedef unsigned short u16;
typedef __attribute__((ext_vector_type(8))) short bh8;        // 8 bf16 raw (4 VGPRs)
typedef __attribute__((ext_vector_type(8))) unsigned short u16x8;
typedef __attribute__((ext_vector_type(4))) float f32x4;
typedef __attribute__((ext_vector_type(4))) unsigned int u32x4;

#define B_ 32
#define T_ 1000
#define D_ 512
#define NG 2048   // 4*D

__device__ __forceinline__ float bf2f(u16 u) {
  union { unsigned int i; float f; } v; v.i = ((unsigned int)u) << 16; return v.f;
}
__device__ __forceinline__ u16 f2bf(float f) {
  union { float f; unsigned int i; } v; v.f = f;
  return (u16)((v.i + 0x7fffu + ((v.i >> 16) & 1u)) >> 16);   // RNE
}

// ---------------- weight transpose + f32->bf16 : dst[C][R] = src[R][C] ----------------
__global__ __launch_bounds__(256) void wtrans_k(const float* __restrict__ src,
                                                u16* __restrict__ dst, int R, int C) {
  __shared__ float tile[32][33];
  const int r0 = blockIdx.x * 32, c0 = blockIdx.y * 32;
  const int tid = threadIdx.x;
#pragma unroll
  for (int q = 0; q < 4; q++) {
    int idx = q * 256 + tid, rr = idx >> 5, cc = idx & 31;
    tile[rr][cc] = src[(size_t)(r0 + rr) * C + c0 + cc];
  }
  __syncthreads();
#pragma unroll
  for (int q = 0; q < 4; q++) {
    int idx = q * 256 + tid, cc = idx >> 5, rr = idx & 31;
    dst[(size_t)(c0 + cc) * R + r0 + rr] = f2bf(tile[rr][cc]);
  }
}

__global__ void bsum_k(const float* __restrict__ a, const float* __restrict__ b,
                       float* __restrict__ o) {
  int i = blockIdx.x * blockDim.x + threadIdx.x;
  if (i < NG) o[i] = a[i] + b[i];
}

// ---------------- x[:, 0:512] = emb[zi[b][t-1]] (0 for t==0), rows ordered (t,b) ----------------
__global__ __launch_bounds__(256) void embed_k(const int* __restrict__ zi,
                                               const float* __restrict__ emb,
                                               u16* __restrict__ x) {
  const int tid = threadIdx.x;
  const int r = blockIdx.x * 4 + (tid >> 6);        // (t*32+b), grid 8000
  const int d0 = (tid & 63) * 8;
  const int t = r >> 5, b = r & 31;
  u16x8 o;
  if (t == 0) {
#pragma unroll
    for (int i = 0; i < 8; i++) o[i] = 0;
  } else {
    const int zv = zi[b * T_ + t - 1];
    const float* s = emb + (size_t)zv * D_ + d0;
#pragma unroll
    for (int i = 0; i < 8; i++) o[i] = f2bf(s[i]);
  }
  *(u16x8*)(x + (size_t)r * 1024 + d0) = o;
}

// ---------------- x[:, 512:1024] = c[b][d][t] transposed (LDS tile) ----------------
__global__ __launch_bounds__(256) void ctrans_k(const float* __restrict__ c,
                                                u16* __restrict__ x) {
  __shared__ float tile[32][65];
  const int b = blockIdx.z, d0 = blockIdx.y * 32, t0 = blockIdx.x * 64;
  const int tid = threadIdx.x;
  const int dd = tid >> 3, tt0 = (tid & 7) * 8;
  const float* src = c + ((size_t)b * D_ + d0 + dd) * T_ + t0 + tt0;
#pragma unroll
  for (int i = 0; i < 8; i++) {
    int tt = tt0 + i;
    tile[dd][tt] = (t0 + tt < T_) ? src[i] : 0.f;
  }
  __syncthreads();
  const int tt = tid & 63, dq = tid >> 6;
  if (t0 + tt < T_) {
    u16x8 o;
#pragma unroll
    for (int i = 0; i < 8; i++) o[i] = f2bf(tile[dq * 8 + i][tt]);
    *(u16x8*)(x + ((size_t)(t0 + tt) * 32 + b) * 1024 + 512 + d0 + dq * 8) = o;
  }
}

// ---------------- bf16 MFMA GEMM: C[M,N] = act(A[M,K] @ Bt[N,K]^T + bias) ----------------
template <bool RELU, bool SCATTER>
__global__ __launch_bounds__(256, 2) void gemm_k(const u16* __restrict__ A,
                                                 const u16* __restrict__ Bt,
                                                 const float* __restrict__ bias,
                                                 void* __restrict__ Cout,
                                                 int M, int N, int K) {
  __shared__ u16 Al[128 * 40];
  __shared__ u16 Bl[128 * 40];
  const int tid = threadIdx.x;
  const int w = tid >> 6, l = tid & 63;
  const int row0 = blockIdx.x * 128, col0 = blockIdx.y * 128;
  const int wr = (w >> 1) * 64, wc = (w & 1) * 64;
  f32x4 acc[4][4];
  const f32x4 zero = {0.f, 0.f, 0.f, 0.f};
#pragma unroll
  for (int i = 0; i < 4; i++)
#pragma unroll
    for (int j = 0; j < 4; j++) acc[i][j] = zero;

  const int sm = tid >> 2;
  const int sk = (tid & 3) * 8;
  const u16* Ap = A + (size_t)(row0 + sm) * K + sk;
  const u16* Bp = Bt + (size_t)(col0 + sm) * K + sk;
  const size_t half = (size_t)64 * K;
  const int ldo = sm * 40 + sk;
  const int lr = l & 15, lk = (l >> 4) * 8;
  const int KT = K >> 5;

  bh8 a0 = *(const bh8*)Ap, a1 = *(const bh8*)(Ap + half);
  bh8 b0 = *(const bh8*)Bp, b1 = *(const bh8*)(Bp + half);

  for (int kt = 0; kt < KT; kt++) {
    const int kn = (kt + 1 < KT) ? (kt + 1) * 32 : 0;
    bh8 na0 = *(const bh8*)(Ap + kn), na1 = *(const bh8*)(Ap + half + kn);
    bh8 nb0 = *(const bh8*)(Bp + kn), nb1 = *(const bh8*)(Bp + half + kn);
    *(bh8*)(Al + ldo) = a0;
    *(bh8*)(Al + ldo + 64 * 40) = a1;
    *(bh8*)(Bl + ldo) = b0;
    *(bh8*)(Bl + ldo + 64 * 40) = b1;
    __syncthreads();
    bh8 af[4], bfr[4];
#pragma unroll
    for (int i = 0; i < 4; i++) af[i] = *(const bh8*)(Al + (wr + i * 16 + lr) * 40 + lk);
#pragma unroll
    for (int j = 0; j < 4; j++) bfr[j] = *(const bh8*)(Bl + (wc + j * 16 + lr) * 40 + lk);
#pragma unroll
    for (int i = 0; i < 4; i++)
#pragma unroll
      for (int j = 0; j < 4; j++)
        acc[i][j] = __builtin_amdgcn_mfma_f32_16x16x32_bf16(af[i], bfr[j], acc[i][j], 0, 0, 0);
    __syncthreads();
    a0 = na0; a1 = na1; b0 = nb0; b1 = nb1;
  }

  const int lrow = (l >> 4) * 4;
#pragma unroll
  for (int j = 0; j < 4; j++) {
    const int n = col0 + wc + j * 16 + lr;
    const float bv = bias[n];
#pragma unroll
    for (int i = 0; i < 4; i++) {
      const int r = row0 + wr + i * 16 + lrow;
      if (SCATTER) {  // out[b][n][t], r = b*T_+t
        const int bb = r / T_;
        const int t = r - bb * T_;
        f32x4 o;
#pragma unroll
        for (int e = 0; e < 4; e++) o[e] = acc[i][j][e] + bv;
        *(f32x4*)((float*)Cout + ((size_t)bb * N + n) * T_ + t) = o;
      } else {
#pragma unroll
        for (int e = 0; e < 4; e++) {
          float v = acc[i][j][e] + bv;
          if (RELU) v = v > 0.f ? v : 0.f;
          ((u16*)Cout)[(size_t)(r + e) * N + n] = f2bf(v);
        }
      }
    }
  }
}

// ---------------- LSTM scan v2: 2 groups x 16 batches; 32 wgs/group, wg owns 16 h-dims.
// h exchange via tag-in-qword relaxed atomics (tag(16b) | h1 | h0). No fences, no counter.
__global__ __launch_bounds__(256, 2) void scan_k(const u16* __restrict__ xg,   // [T*B][2048] rows (t,b)
                                                 const u16* __restrict__ Whht, // [2048][512]
                                                 u16* __restrict__ hs,         // [B*T][512]
                                                 unsigned long long* hbuf) {   // [2][32][256] tagged qwords
  __shared__ u16 hstage[16 * 512];        // 16 A-frags x (64 lanes x 8 bf16) = 16 KB, frag-linear
  __shared__ float gl[16][65];            // [batch][gate*16 + dim], stride 65 (conflict-light)
  const int tid = threadIdx.x;
  const int wgid = blockIdx.x;
  const int grp = wgid >> 5;              // 0..1   (16 batches each)
  const int wgin = wgid & 31;             // 0..31  (16 h-dims each)
  const int D0 = wgin * 16;
  const int bbase = grp * 16;
  const int w = tid >> 6, l = tid & 63;
  const int lr = l & 15, lc = l >> 4;
  const int lk8 = lc * 8;

  // loop-invariant B fragments: wave w = gate w, cols D0..D0+15 (64 VGPRs)
  bh8 bfr[16];
  {
    const u16* wp = Whht + (size_t)(w * 512 + D0 + lr) * 512 + lk8;
#pragma unroll
    for (int kk = 0; kk < 16; kk++) bfr[kk] = *(const bh8*)(wp + kk * 32);
  }

  // h_{-1} = 0
  for (int i = tid; i < 16 * 256; i += 256) ((unsigned int*)hstage)[i] = 0u;

  const int pb = (tid >> 3) & 15, pd = tid & 7;   // pointwise mapping (tid < 128)
  const int gb = bbase + pb;                      // global batch
  float cc0 = 0.f, cc1 = 0.f;
  unsigned int xgu[4];
  if (tid < 128) {
    const u16* xp = xg + (size_t)gb * NG + D0 + 2 * pd;      // t = 0 rows
#pragma unroll
    for (int g = 0; g < 4; g++) xgu[g] = *(const unsigned int*)(xp + g * 512);
  }
  __syncthreads();

  for (int t = 0; t < T_; t++) {
    // ---- gates = h_{t-1} @ Whh (one 16x16 tile per wave, K=512) ----
    f32x4 acc = {0.f, 0.f, 0.f, 0.f};
#pragma unroll
    for (int kk = 0; kk < 16; kk++) {
      bh8 af = *(const bh8*)(hstage + kk * 512 + l * 8);
      acc = __builtin_amdgcn_mfma_f32_16x16x32_bf16(af, bfr[kk], acc, 0, 0, 0);
    }
#pragma unroll
    for (int e = 0; e < 4; e++) gl[lc * 4 + e][w * 16 + lr] = acc[e];
    __syncthreads();                                        // B1

    if (tid < 128) {
      // ---- pointwise: dims (D0+2pd, D0+2pd+1), batch gb ----
      const float i0 = gl[pb][ 0 + 2 * pd]     + bf2f((u16)(xgu[0] & 0xffffu));
      const float i1 = gl[pb][ 0 + 2 * pd + 1] + bf2f((u16)(xgu[0] >> 16));
      const float f0 = gl[pb][16 + 2 * pd]     + bf2f((u16)(xgu[1] & 0xffffu));
      const float f1 = gl[pb][16 + 2 * pd + 1] + bf2f((u16)(xgu[1] >> 16));
      const float g0 = gl[pb][32 + 2 * pd]     + bf2f((u16)(xgu[2] & 0xffffu));
      const float g1 = gl[pb][32 + 2 * pd + 1] + bf2f((u16)(xgu[2] >> 16));
      const float o0 = gl[pb][48 + 2 * pd]     + bf2f((u16)(xgu[3] & 0xffffu));
      const float o1 = gl[pb][48 + 2 * pd + 1] + bf2f((u16)(xgu[3] >> 16));
      const float si0 = 1.f / (1.f + __expf(-i0)), si1 = 1.f / (1.f + __expf(-i1));
      const float sf0 = 1.f / (1.f + __expf(-f0)), sf1 = 1.f / (1.f + __expf(-f1));
      const float tg0 = 1.f - 2.f / (__expf(2.f * g0) + 1.f);
      const float tg1 = 1.f - 2.f / (__expf(2.f * g1) + 1.f);
      const float so0 = 1.f / (1.f + __expf(-o0)), so1 = 1.f / (1.f + __expf(-o1));
      cc0 = sf0 * cc0 + si0 * tg0;
      cc1 = sf1 * cc1 + si1 * tg1;
      const float h0v = so0 * (1.f - 2.f / (__expf(2.f * cc0) + 1.f));
      const float h1v = so1 * (1.f - 2.f / (__expf(2.f * cc1) + 1.f));
      const unsigned int pk = ((unsigned int)f2bf(h1v) << 16) | (unsigned int)f2bf(h0v);
      *(unsigned int*)(hs + ((size_t)gb * T_ + t) * 512 + D0 + 2 * pd) = pk;
      if (t + 1 < T_) {
        const unsigned long long qv = ((unsigned long long)(t + 1) << 48) | (unsigned long long)pk;
        __hip_atomic_store(hbuf + ((size_t)((t & 1) * 32 + gb)) * 256 + wgin * 8 + pd, qv,
                           __ATOMIC_RELAXED, __HIP_MEMORY_SCOPE_AGENT);
        const u16* xp = xg + ((size_t)(t + 1) * 32 + gb) * NG + D0 + 2 * pd;
#pragma unroll
        for (int g = 0; g < 4; g++) xgu[g] = *(const unsigned int*)(xp + g * 512);
      }
    } else if (t + 1 < T_) {
      // ---- waves 2-3: poll tagged qwords, stage h_t as MFMA A-frags ----
      const int kk0 = (w - 2) * 8;
      const unsigned long long tagv = (unsigned long long)(t + 1);
      const unsigned long long* hb =
          hbuf + ((size_t)((t & 1) * 32 + bbase + lr)) * 256 + 4 * lc;
      for (int s = 0; s < 8; s++) {
        const int kk = kk0 + s;
        const unsigned long long* p = hb + 16 * kk;
        unsigned long long q0, q1, q2, q3;
        do {
          q0 = __hip_atomic_load(p + 0, __ATOMIC_RELAXED, __HIP_MEMORY_SCOPE_AGENT);
          q1 = __hip_atomic_load(p + 1, __ATOMIC_RELAXED, __HIP_MEMORY_SCOPE_AGENT);
          q2 = __hip_atomic_load(p + 2, __ATOMIC_RELAXED, __HIP_MEMORY_SCOPE_AGENT);
          q3 = __hip_atomic_load(p + 3, __ATOMIC_RELAXED, __HIP_MEMORY_SCOPE_AGENT);
        } while (__ballot(((q0 >> 48) != tagv) || ((q1 >> 48) != tagv) ||
                          ((q2 >> 48) != tagv) || ((q3 >> 48) != tagv)));
        u32x4 pk4 = {(unsigned int)q0, (unsigned int)q1, (unsigned int)q2, (unsigned int)q3};
        *(u32x4*)(hstage + (size_t)kk * 512 + (size_t)l * 8) = pk4;
      }
    }
    __syncthreads();                                        // B2: hstage(t) ready
  }
}

extern "C" void kernel_launch(void* const* d_in, const int* in_sizes, int n_in,
                              void* d_out, int out_size, void* d_ws, size_t ws_size,
                              hipStream_t stream) {
  const int*   zi    = (const int*)d_in[0];
  const float* c     = (const float*)d_in[1];
  const float* emb   = (const float*)d_in[2];
  const float* W1    = (const float*)d_in[3];
  const float* b1    = (const float*)d_in[4];
  const float* W2    = (const float*)d_in[5];
  const float* b2    = (const float*)d_in[6];
  const float* W_ih  = (const float*)d_in[7];
  const float* b_ih  = (const float*)d_in[8];
  const float* W_hh  = (const float*)d_in[9];
  const float* b_hh  = (const float*)d_in[10];
  const float* W_out = (const float*)d_in[11];
  const float* b_out = (const float*)d_in[12];
  float* out = (float*)d_out;
  char* ws = (char*)d_ws;

  const size_t x_off   = 0;
  const size_t xg_off  = 65536000;
  const size_t pre_off = 32768000;
  const size_t w_off   = xg_off + 131072000;
  u16* xb    = (u16*)(ws + x_off);
  u16* hsb   = (u16*)(ws + x_off);
  u16* preb  = (u16*)(ws + pre_off);
  u16* xgb   = (u16*)(ws + xg_off);
  u16* h1b   = (u16*)(ws + xg_off);
  u16* W1t   = (u16*)(ws + w_off);           // [512][1024]
  u16* W2t   = W1t + 512 * 1024;             // [512][512]
  u16* Wiht  = W2t + 512 * 512;              // [2048][512]
  u16* Whht  = Wiht + 2048 * 512;            // [2048][512]
  u16* Woutt = Whht + 2048 * 512;            // [512][512]
  float* bsum = (float*)(Woutt + 512 * 512);
  unsigned long long* hbuf = (unsigned long long*)(bsum + NG);  // [2][32][256]

  hipMemsetAsync(hbuf, 0, 2 * 32 * 256 * sizeof(unsigned long long), stream);

  wtrans_k<<<dim3(32, 16), 256, 0, stream>>>(W1, W1t, 1024, 512);
  wtrans_k<<<dim3(16, 16), 256, 0, stream>>>(W2, W2t, 512, 512);
  wtrans_k<<<dim3(16, 64), 256, 0, stream>>>(W_ih, Wiht, 512, 2048);
  wtrans_k<<<dim3(16, 64), 256, 0, stream>>>(W_hh, Whht, 512, 2048);
  wtrans_k<<<dim3(16, 16), 256, 0, stream>>>(W_out, Woutt, 512, 512);
  bsum_k<<<8, 256, 0, stream>>>(b_ih, b_hh, bsum);
  embed_k<<<8000, 256, 0, stream>>>(zi, emb, xb);
  ctrans_k<<<dim3(16, 16, 32), 256, 0, stream>>>(c, xb);

  gemm_k<true,  false><<<dim3(250, 4),  256, 0, stream>>>(xb,   W1t,   b1,    h1b,  32000, 512,  1024);
  gemm_k<false, false><<<dim3(250, 4),  256, 0, stream>>>(h1b,  W2t,   b2,    preb, 32000, 512,  512);
  gemm_k<false, false><<<dim3(250, 16), 256, 0, stream>>>(preb, Wiht,  bsum,  xgb,  32000, 2048, 512);
  scan_k<<<64, 256, 0, stream>>>(xgb, Whht, hsb, hbuf);
  gemm_k<false, true ><<<dim3(250, 4),  256, 0, stream>>>(hsb,  Woutt, b_out, out,  32000, 512,  512);
}